// Round 10
// baseline (371.094 us; speedup 1.0000x reference)
//
#include <hip/hip_runtime.h>
#include <hip/hip_bf16.h>
#include <hip/hip_cooperative_groups.h>

namespace cg = cooperative_groups;

#define NN   10000
#define EE   160000
#define CINC 32
#define COUTC 32
#define RRR  6
#define MMM  3
#define RM   (RRR*MMM)      // 18
#define KK   (RM*CINC)      // 576
#define KE   608            // extended K: 576 + 32 residual block
#define NPB  4              // nodes per virtual block (one wave each), 256 threads
#define NVB  (NN/NPB)       // 2500 virtual conv blocks
#define CAP  64             // fixed bucket capacity per node (mean degree 16)
#define AROW 624            // agg row stride in bf16 elems (608 + 16 pad)
#define WSZ  19456          // shorts per Wt plane: 19*2*64*8
#define EPSV 1e-8f

typedef __attribute__((ext_vector_type(8))) short bf16x8;
typedef __attribute__((ext_vector_type(4))) float f32x4;
typedef __attribute__((ext_vector_type(16))) float f32x16;

__device__ inline short f2bf(float f) {            // native cast -> cvt_pk fusable
    __hip_bfloat16 b = __float2bfloat16(f);
    union { __hip_bfloat16 b; short s; } u; u.b = b;
    return u.s;
}
__device__ inline float bf2f(unsigned short h) {
    return __uint_as_float(((unsigned)h) << 16);
}
// split fp32 -> (hi, lo) bf16 pair, packed: x = rehi|relo<<16, y = imhi|imlo<<16
__device__ inline uint2 packsplit(float re, float im) {
    unsigned short rh = (unsigned short)f2bf(re);
    unsigned short rl = (unsigned short)f2bf(re - bf2f(rh));
    unsigned short ih = (unsigned short)f2bf(im);
    unsigned short il = (unsigned short)f2bf(im - bf2f(ih));
    return make_uint2((unsigned)rh | ((unsigned)rl << 16),
                      (unsigned)ih | ((unsigned)il << 16));
}

// ---------------- conv virtual-block body (r9-verified, blockIdx -> vb) ----------------
// In-register MFMA aggregation (no LDS staging, 2-tile register double-buffer,
// split sei load) + fragment-major bf16 MFMA einsum with fused residual K-block.
__device__ __forceinline__ void conv_block(
    bool fin, int vb,
    const uint2* __restrict__ xin,      // (NN,32) packed split-bf16 input
    const int*  __restrict__ cnts,      // (NN) per-node edge count (unclamped)
    const int2* __restrict__ sei,       // (NN*CAP) (src,eid) buckets
    const float4* __restrict__ stenc4,  // (EE,9) float4 = (EE,18) complex
    const short* __restrict__ Wcb,      // fragment-major [re|im] planes (19 r-blocks)
    const float* __restrict__ bias,     // (32)
    const float2* __restrict__ xres,    // (NN,32) original xc (fin only)
    float2* __restrict__ out,           // (NN,32) complex (fin)
    uint2* __restrict__ outbf,          // packed split-bf16 h (!fin)
    short* aggS)                        // 2*NPB*AROW shorts LDS
{
    int t = threadIdx.x;
    int g = t >> 6;                     // wave = node slot 0..3
    int l = t & 63;
    int c = l & 31;                     // channel (B col) == rm row index for A
    int oct = l >> 5;
    int n = vb*NPB + g;                 // node id: computable, no load

    // ---- aggregation via MFMA ----
    f32x16 Pre = (f32x16)(0.f), Pim = (f32x16)(0.f);
    {
        // sei load: lanes<32 immediate (no dependency), lanes>=32 wait on cnt
        int2 v0 = make_int2(0, 0);
        if (l < 32) v0 = sei[n*CAP + l];
        int cnt = cnts[n]; if (cnt > CAP) cnt = CAP;
        if (l >= 32 && l < cnt) v0 = sei[n*CAP + l];
        int srcAll = (l < cnt) ? v0.x : 0;
        int eidAll = (l < cnt) ? v0.y : 0;

        bool rmok = (c < RM);                       // A row valid
        int rmo = ((c >> 1) << 4) + ((c & 1) << 3); // byte offset of (re,im) in record
        const char* sb = (const char*)stenc4;
        int ntiles = (cnt + 15) >> 4;

        union P { unsigned u[4]; short s[8]; bf16x8 v; };
        float2 sv[8], svn[8];
        uint2  xv[8], xvn[8];

        auto tload = [&](int ck, float2* svp, uint2* xvp) {
            int ebase = ck*16 + oct*8;
            #pragma unroll
            for (int j = 0; j < 8; ++j) {
                int e = ebase + j;
                int eid = __shfl(eidAll, e, 64);
                int s   = __shfl(srcAll, e, 64);
                bool ok = rmok && (e < cnt);
                float2 vv = make_float2(0.f, 0.f);
                if (ok) vv = *(const float2*)(sb + (size_t)eid*144 + rmo);
                svp[j] = vv;
                xvp[j] = xin[(s << 5) | c];         // src 0 for tail: killed by zero A
            }
        };
        auto tcompute = [&](const float2* svp, const uint2* xvp) {
            P Are, Aim, AimN;
            #pragma unroll
            for (int j = 0; j < 8; ++j) {
                Are.s[j] = f2bf(svp[j].x);
                Aim.s[j] = f2bf(svp[j].y);
            }
            #pragma unroll
            for (int k2 = 0; k2 < 4; ++k2) AimN.u[k2] = Aim.u[k2] ^ 0x80008000u;
            P B;
            #pragma unroll
            for (int k2 = 0; k2 < 4; ++k2)          // Brh: re hi
                B.u[k2] = (xvp[2*k2].x & 0xffffu) | (xvp[2*k2+1].x << 16);
            Pre = __builtin_amdgcn_mfma_f32_32x32x16_bf16(Are.v, B.v, Pre, 0, 0, 0);
            Pim = __builtin_amdgcn_mfma_f32_32x32x16_bf16(Aim.v, B.v, Pim, 0, 0, 0);
            #pragma unroll
            for (int k2 = 0; k2 < 4; ++k2)          // Brl: re lo
                B.u[k2] = (xvp[2*k2].x >> 16) | (xvp[2*k2+1].x & 0xffff0000u);
            Pre = __builtin_amdgcn_mfma_f32_32x32x16_bf16(Are.v, B.v, Pre, 0, 0, 0);
            Pim = __builtin_amdgcn_mfma_f32_32x32x16_bf16(Aim.v, B.v, Pim, 0, 0, 0);
            #pragma unroll
            for (int k2 = 0; k2 < 4; ++k2)          // Bih: im hi
                B.u[k2] = (xvp[2*k2].y & 0xffffu) | (xvp[2*k2+1].y << 16);
            Pre = __builtin_amdgcn_mfma_f32_32x32x16_bf16(AimN.v, B.v, Pre, 0, 0, 0);
            Pim = __builtin_amdgcn_mfma_f32_32x32x16_bf16(Are.v, B.v, Pim, 0, 0, 0);
            #pragma unroll
            for (int k2 = 0; k2 < 4; ++k2)          // Bil: im lo
                B.u[k2] = (xvp[2*k2].y >> 16) | (xvp[2*k2+1].y & 0xffff0000u);
            Pre = __builtin_amdgcn_mfma_f32_32x32x16_bf16(AimN.v, B.v, Pre, 0, 0, 0);
            Pim = __builtin_amdgcn_mfma_f32_32x32x16_bf16(Are.v, B.v, Pim, 0, 0, 0);
        };

        if (ntiles > 0) {
            tload(0, sv, xv);
            for (int ck = 0; ck < ntiles; ++ck) {
                bool more = (ck + 1 < ntiles);
                if (more) tload(ck+1, svn, xvn);
                tcompute(sv, xv);
                if (more) {
                    #pragma unroll
                    for (int j = 0; j < 8; ++j) { sv[j] = svn[j]; xv[j] = xvn[j]; }
                }
            }
        }

        // C-extract: rows rm<18 -> aggS bf16 (deg==0 waves write zeros)
        short* aR = aggS + g*AROW;
        short* aI = aggS + NPB*AROW + g*AROW;
        #pragma unroll
        for (int reg = 0; reg < 16; ++reg) {
            int rm = (reg & 3) + 8*(reg >> 2) + 4*oct;
            if (rm < RM) {
                aR[rm*32 + c] = f2bf(Pre[reg]);
                aI[rm*32 + c] = f2bf(Pim[reg]);
            }
        }
        // residual K-block rows (fin: x, else zeros)
        if (l < 32) {
            float2 xvv = make_float2(0.f, 0.f);
            if (fin) xvv = xres[(size_t)n*CINC + l];
            aR[KK + l] = f2bf(xvv.x);
            aI[KK + l] = f2bf(xvv.y);
        }
    }
    __syncthreads();

    // ---- einsum via MFMA: D[m][d] = sum_k agg[m][k] * Wc[k][d], K=608 ----
    int quad = l >> 4;
    int nn16 = l & 15;
    int mrow = (nn16 < NPB) ? nn16 : NPB-1;       // rows >=4 ignored (dup of 3)
    int rm0 = (g < 3) ? 5*g : 15;                 // waves: 5,5,5,4 r-steps
    int nrm = (g < 3) ? 5 : 4;
    const short* aggR = aggS;
    const short* aggI = aggS + NPB*AROW;
    const short* Wr = Wcb;
    const short* Wi = Wcb + WSZ;
    int lbase = l*8;

    f32x4 Dre[2], Dim[2];
    #pragma unroll
    for (int nt = 0; nt < 2; ++nt) { Dre[nt] = (f32x4)(0.f); Dim[nt] = (f32x4)(0.f); }
    union PU { unsigned u[4]; bf16x8 v; };
    for (int r = rm0; r < rm0 + nrm; ++r) {
        int koff = r*32 + quad*8;
        bf16x8 ar = *(const bf16x8*)(aggR + mrow*AROW + koff);
        PU ai, ain;
        ai.v = *(const bf16x8*)(aggI + mrow*AROW + koff);
        #pragma unroll
        for (int k2 = 0; k2 < 4; ++k2) ain.u[k2] = ai.u[k2] ^ 0x80008000u;
        #pragma unroll
        for (int nt = 0; nt < 2; ++nt) {
            int woff = ((r*2 + nt) << 9) + lbase;     // fragment-major, coalesced
            bf16x8 br = *(const bf16x8*)(Wr + woff);
            bf16x8 bi = *(const bf16x8*)(Wi + woff);
            Dre[nt] = __builtin_amdgcn_mfma_f32_16x16x32_bf16(ar,    br, Dre[nt], 0, 0, 0);
            Dre[nt] = __builtin_amdgcn_mfma_f32_16x16x32_bf16(ain.v, bi, Dre[nt], 0, 0, 0);
            Dim[nt] = __builtin_amdgcn_mfma_f32_16x16x32_bf16(ar,    bi, Dim[nt], 0, 0, 0);
            Dim[nt] = __builtin_amdgcn_mfma_f32_16x16x32_bf16(ai.v,  br, Dim[nt], 0, 0, 0);
        }
    }
    __syncthreads();                    // all agg reads done; reuse as dump

    // ---- dump partials: [wave][m][d] float2, rows m<4 only (quad 0) ----
    float2* dump = (float2*)aggS;       // 4096 B <= 9984
    if (quad == 0) {
        #pragma unroll
        for (int reg = 0; reg < 4; ++reg) {
            int m = reg;
            #pragma unroll
            for (int nt = 0; nt < 2; ++nt) {
                int d = nt*16 + nn16;
                dump[((size_t)g*NPB + m)*COUTC + d] =
                    make_float2(Dre[nt][reg], Dim[nt][reg]);
            }
        }
    }
    __syncthreads();

    // ---- reduce 4 waves, nonlinearity (residual already in einsum) ----
    if (t < NPB*COUTC) {
        int m = t >> 5, d = t & 31;
        int nn = vb*NPB + m;
        float2 hv = make_float2(0.f, 0.f);
        #pragma unroll
        for (int w = 0; w < NPB; ++w) {
            float2 v = dump[((size_t)w*NPB + m)*COUTC + d];
            hv.x += v.x; hv.y += v.y;
        }
        float mag = sqrtf(hv.x*hv.x + hv.y*hv.y);
        float num = mag + bias[d]; if (num < 0.f) num = 0.f;
        float den = (mag > EPSV) ? mag : EPSV;
        float f = num / den;
        if (fin) out[(size_t)nn*COUTC + d] = make_float2(f*hv.x, f*hv.y);
        else     outbf[(size_t)nn*COUTC + d] = packsplit(f*hv.x, f*hv.y);
    }
}

// ---------------- persistent cooperative megakernel ----------------
// phase 0: zero cursor. phase 1: build (weights + bucket scatter + x split).
// phase 2: conv1 (virtual blocks, grid-stride). phase 3: conv2.
// grid.sync() between phases replaces 3 kernel-launch boundaries (+memset).
__global__ void __launch_bounds__(256, 4)
k_mega(const int* __restrict__ edges, int* __restrict__ cursor,
       const float* __restrict__ w1, const float* __restrict__ off1,
       const float* __restrict__ w2, const float* __restrict__ off2,
       short* __restrict__ Wcb1, short* __restrict__ Wcb2,
       int2* __restrict__ sei,
       const float2* __restrict__ xc, uint2* __restrict__ xbf,
       const float2* __restrict__ resw,
       const float4* __restrict__ stenc4,
       const float* __restrict__ b1, const float* __restrict__ b2,
       uint2* __restrict__ hbf, float2* __restrict__ out)
{
    cg::grid_group grid = cg::this_grid();
    __shared__ __align__(16) short aggS[2*NPB*AROW];     // 9984 B
    int gtid = blockIdx.x*blockDim.x + threadIdx.x;
    int gsz  = gridDim.x*blockDim.x;

    // ---- phase 0: zero cursor ----
    for (int i = gtid; i < NN; i += gsz) cursor[i] = 0;
    grid.sync();

    // ---- phase 1: build ----
    for (int i = gtid; i < NN*CINC; i += gsz) {
        if (i < KK*COUTC) {
            int d = i & 31;
            int k = i >> 5;                 // einsum K index = rm*32 + c
            int c = k & 31;
            int r_ = k >> 5;                // 0..17
            int q  = (k >> 3) & 3;          // quad within r
            int kk = k & 7;
            int l  = q*16 + (d & 15);
            int n2 = d >> 4;
            int addr = ((r_*2 + n2)*64 + l)*8 + kk;
            float o1 = off1[c*COUTC + d];
            float o2 = off2[c*COUTC + d];
            float s1 = sinf(o1), c1 = cosf(o1);
            float s2 = sinf(o2), c2 = cosf(o2);
            Wcb1[addr]       = f2bf(w1[i]*c1);
            Wcb1[WSZ + addr] = f2bf(w1[i]*s1);
            Wcb2[addr]       = f2bf(w2[i]*c2);
            Wcb2[WSZ + addr] = f2bf(w2[i]*s2);
        }
        if (i < 1024) {                     // residual K-block (r=18)
            int n2 = i >> 9;
            int l2 = (i >> 3) & 63;
            int kk = i & 7;
            int c  = ((l2 >> 4) << 3) + kk;
            int d  = (n2 << 4) + (l2 & 15);
            int addr = ((18*2 + n2)*64 + l2)*8 + kk;
            float2 rv = resw[c*COUTC + d];
            Wcb2[addr]       = f2bf(rv.x);
            Wcb2[WSZ + addr] = f2bf(rv.y);
            Wcb1[addr]       = 0;
            Wcb1[WSZ + addr] = 0;
        }
        if (i < EE) {
            int src = edges[2*i];
            int tgt = edges[2*i+1];
            int pos = atomicAdd(&cursor[tgt], 1);
            if (pos < CAP) sei[tgt*CAP + pos] = make_int2(src, i);
        }
        if (i < NN*CINC) {
            float2 v = xc[i];
            xbf[i] = packsplit(v.x, v.y);
        }
    }
    grid.sync();

    // ---- phase 2: conv1 ----
    for (int vb = blockIdx.x; vb < NVB; vb += gridDim.x) {
        conv_block(false, vb, xbf, cursor, sei, stenc4, Wcb1, b1,
                   xc, out, hbf, aggS);
        __syncthreads();                // LDS reuse guard between virtual blocks
    }
    grid.sync();

    // ---- phase 3: conv2 ----
    for (int vb = blockIdx.x; vb < NVB; vb += gridDim.x) {
        conv_block(true, vb, hbf, cursor, sei, stenc4, Wcb2, b2,
                   xc, out, hbf, aggS);
        __syncthreads();
    }
}

// ---------------- launch ----------------
extern "C" void kernel_launch(void* const* d_in, const int* in_sizes, int n_in,
                              void* d_out, int out_size, void* d_ws, size_t ws_size,
                              hipStream_t stream) {
    const int*   edges = (const int*)  d_in[1];    // (E,2)
    const float2* xc   = (const float2*)d_in[0];   // (N,32,2) -> complex
    const float4* stenc4 = (const float4*)d_in[2]; // (E,6,3,2) -> (E,9) float4
    const float* w1    = (const float*)d_in[3];
    const float* off1  = (const float*)d_in[4];
    const float* b1    = (const float*)d_in[5];
    const float* w2    = (const float*)d_in[6];
    const float* off2  = (const float*)d_in[7];
    const float* b2    = (const float*)d_in[8];
    const float2* resw = (const float2*)d_in[9];   // (32,32) complex
    float2* out = (float2*)d_out;

    char* ws = (char*)d_ws;
    size_t o = 0;
    auto alloc = [&](size_t bytes) {
        o = (o + 255) & ~(size_t)255;
        size_t r = o; o += bytes; return r;
    };
    int*    cursor = (int*)  (ws + alloc(NN*sizeof(int)));
    int2*   sei    = (int2*) (ws + alloc((size_t)NN*CAP*sizeof(int2)));
    short*  Wcb1   = (short*)(ws + alloc((size_t)2*WSZ*sizeof(short)));
    short*  Wcb2   = (short*)(ws + alloc((size_t)2*WSZ*sizeof(short)));
    uint2*  xbf    = (uint2*)(ws + alloc((size_t)NN*CINC*sizeof(uint2)));
    uint2*  hbf    = (uint2*)(ws + alloc((size_t)NN*CINC*sizeof(uint2)));
    (void)ws_size; (void)in_sizes; (void)n_in; (void)out_size;

    // grid sized for guaranteed co-residency (cached occupancy query)
    static int nblk = 0;
    if (nblk == 0) {
        int maxb = 0;
        hipOccupancyMaxActiveBlocksPerMultiprocessor(&maxb, k_mega, 256, 0);
        int ncu = 256;
        hipDeviceProp_t prop;
        int dev = 0;
        if (hipGetDevice(&dev) == hipSuccess &&
            hipGetDeviceProperties(&prop, dev) == hipSuccess)
            ncu = prop.multiProcessorCount;
        if (maxb < 1) maxb = 4;
        nblk = maxb * ncu;
        if (nblk > NVB) nblk = NVB;
        if (nblk < 64) nblk = 64;
    }

    void* args[] = {
        (void*)&edges, (void*)&cursor,
        (void*)&w1, (void*)&off1, (void*)&w2, (void*)&off2,
        (void*)&Wcb1, (void*)&Wcb2, (void*)&sei,
        (void*)&xc, (void*)&xbf, (void*)&resw,
        (void*)&stenc4,
        (void*)&b1, (void*)&b2,
        (void*)&hbf, (void*)&out
    };
    hipLaunchCooperativeKernel((const void*)k_mega, dim3(nblk), dim3(256),
                               args, 0, stream);
}

// Round 11
// 144.548 us; speedup vs baseline: 2.5673x; 2.5673x over previous
//
#include <hip/hip_runtime.h>
#include <hip/hip_bf16.h>

#define NN   10000
#define EE   160000
#define CINC 32
#define COUTC 32
#define RRR  6
#define MMM  3
#define RM   (RRR*MMM)      // 18
#define KK   (RM*CINC)      // 576
#define NPB  4              // nodes per block (one wave each), 256 threads
#define CAP  64             // fixed bucket capacity per node (mean degree 16)
#define AROW 624            // agg row stride in bf16 elems (608 + 16 pad)
#define WSZ  19456          // shorts per Wt plane: 19*2*64*8
#define EPSV 1e-8f

typedef __attribute__((ext_vector_type(8))) short bf16x8;
typedef __attribute__((ext_vector_type(4))) float f32x4;
typedef __attribute__((ext_vector_type(16))) float f32x16;

__device__ inline short f2bf(float f) {            // native cast -> cvt_pk fusable
    __hip_bfloat16 b = __float2bfloat16(f);
    union { __hip_bfloat16 b; short s; } u; u.b = b;
    return u.s;
}
__device__ inline float bf2f(unsigned short h) {
    return __uint_as_float(((unsigned)h) << 16);
}
// split fp32 -> (hi, lo) bf16 pair, packed: x = rehi|relo<<16, y = imhi|imlo<<16
__device__ inline uint2 packsplit(float re, float im) {
    unsigned short rh = (unsigned short)f2bf(re);
    unsigned short rl = (unsigned short)f2bf(re - bf2f(rh));
    unsigned short ih = (unsigned short)f2bf(im);
    unsigned short il = (unsigned short)f2bf(im - bf2f(ih));
    return make_uint2((unsigned)rh | ((unsigned)rl << 16),
                      (unsigned)ih | ((unsigned)il << 16));
}

// ---------------- build: weight planes + bucket scatter + x split + bf16 stencil ----------------
// Wt layout: addr(plane, r, n2, lane, kk) = plane*WSZ + ((r*2+n2)*64 + lane)*8 + kk.
// r=0..17: einsum K index k = r*32 + quad*8 + kk. r=18: residual block (Wcb2=resw,
// Wcb1=0). NEW: stbf[eid*18 + rm] = (imbf16<<16)|rebf16 -- 72B/record, converted
// ONCE here instead of per-gather in both convs (same rounding point -> identical math).
__global__ void __launch_bounds__(256)
k_build(const int* __restrict__ edges, int* __restrict__ cursor,
        const float* __restrict__ w1, const float* __restrict__ off1,
        const float* __restrict__ w2, const float* __restrict__ off2,
        short* __restrict__ Wcb1, short* __restrict__ Wcb2,
        int2* __restrict__ sei,
        const float2* __restrict__ xc, uint2* __restrict__ xbf,
        const float2* __restrict__ resw,
        const float2* __restrict__ stenc2, unsigned* __restrict__ stbf)
{
    int i = blockIdx.x*blockDim.x + threadIdx.x;
    if (i < KK*COUTC) {
        int d = i & 31;
        int k = i >> 5;                 // einsum K index = rm*32 + c
        int c = k & 31;
        int r_ = k >> 5;                // 0..17
        int q  = (k >> 3) & 3;          // quad within r
        int kk = k & 7;
        int l  = q*16 + (d & 15);
        int n2 = d >> 4;
        int addr = ((r_*2 + n2)*64 + l)*8 + kk;
        float o1 = off1[c*COUTC + d];
        float o2 = off2[c*COUTC + d];
        float s1 = sinf(o1), c1 = cosf(o1);
        float s2 = sinf(o2), c2 = cosf(o2);
        Wcb1[addr]       = f2bf(w1[i]*c1);
        Wcb1[WSZ + addr] = f2bf(w1[i]*s1);
        Wcb2[addr]       = f2bf(w2[i]*c2);
        Wcb2[WSZ + addr] = f2bf(w2[i]*s2);
    }
    if (i < 1024) {                     // residual K-block (r=18): n2(2) x lane(64) x kk(8)
        int n2 = i >> 9;
        int l2 = (i >> 3) & 63;
        int kk = i & 7;
        int c  = ((l2 >> 4) << 3) + kk;
        int d  = (n2 << 4) + (l2 & 15);
        int addr = ((18*2 + n2)*64 + l2)*8 + kk;
        float2 rv = resw[c*COUTC + d];
        Wcb2[addr]       = f2bf(rv.x);
        Wcb2[WSZ + addr] = f2bf(rv.y);
        Wcb1[addr]       = 0;
        Wcb1[WSZ + addr] = 0;
    }
    if (i < EE) {
        int src = edges[2*i];
        int tgt = edges[2*i+1];
        int pos = atomicAdd(&cursor[tgt], 1);
        if (pos < CAP) sei[tgt*CAP + pos] = make_int2(src, i);
    }
    if (i < NN*CINC) {
        float2 v = xc[i];
        xbf[i] = packsplit(v.x, v.y);
    }
    // bf16 stencil pack: grid covers EE*18 = 2.88M > 320K threads -> stride loop.
    // Element e = eid*18 + rm; contiguous reads (float2) and writes (uint).
    for (int e = i; e < EE*RM; e += 320000) {
        float2 s = stenc2[e];
        stbf[e] = ((unsigned)(unsigned short)f2bf(s.x)) |
                  (((unsigned)(unsigned short)f2bf(s.y)) << 16);
    }
}

// ---------------- fused conv: in-register MFMA aggregation + bf16 MFMA einsum ----------------
// r9-verified structure. NO degree sort: node id = blockIdx*NPB + wave. Split sei
// load (lanes<32 immediate). 16-edge K-tiles, 2-tile register double-buffer.
// A-gather now 4B/lane from pre-packed bf16 stencil (72B record ~1.1 cache lines);
// A-plane build is 8 low/high-half repacks instead of 16 cvts. Einsum: fragment-
// major Wcb, fused residual K-block, 2-accumulator complex form.
template<bool FINAL>
__global__ void __launch_bounds__(256, 4)
k_conv(const uint2* __restrict__ xbf,      // (NN,32) packed split-bf16 input
       const int*  __restrict__ cnts,      // (NN) per-node edge count (unclamped)
       const int2* __restrict__ sei,       // (NN*CAP) (src,eid) buckets
       const unsigned* __restrict__ stbf,  // (EE,18) packed bf16 stencil
       const short* __restrict__ Wcb,      // fragment-major [re|im] planes (19 r-blocks)
       const float* __restrict__ bias,     // (32)
       const float2* __restrict__ xres,    // (NN,32) original xc (FINAL only)
       float2* __restrict__ out,           // (NN,32) complex (FINAL)
       uint2* __restrict__ outbf)          // packed split-bf16 h (!FINAL)
{
    __shared__ __align__(16) short aggS[2*NPB*AROW];     // 9984 B; later dump
    int t = threadIdx.x;
    int g = t >> 6;                     // wave = node slot 0..3
    int l = t & 63;
    int c = l & 31;                     // channel (B col) == rm row index for A
    int oct = l >> 5;
    int n = blockIdx.x*NPB + g;         // node id: computable, no load

    // ---- aggregation via MFMA ----
    f32x16 Pre = (f32x16)(0.f), Pim = (f32x16)(0.f);
    {
        // sei load: lanes<32 immediate (no dependency), lanes>=32 wait on cnt
        int2 v0 = make_int2(0, 0);
        if (l < 32) v0 = sei[n*CAP + l];
        int cnt = cnts[n]; if (cnt > CAP) cnt = CAP;
        if (l >= 32 && l < cnt) v0 = sei[n*CAP + l];
        int srcAll = (l < cnt) ? v0.x : 0;
        int eidAll = (l < cnt) ? v0.y : 0;

        bool rmok = (c < RM);                       // A row valid
        int ntiles = (cnt + 15) >> 4;

        union P { unsigned u[4]; short s[8]; bf16x8 v; };
        unsigned sw[8], swn[8];
        uint2    xv[8], xvn[8];

        auto tload = [&](int ck, unsigned* swp, uint2* xvp) {
            int ebase = ck*16 + oct*8;
            #pragma unroll
            for (int j = 0; j < 8; ++j) {
                int e = ebase + j;
                int eid = __shfl(eidAll, e, 64);
                int s   = __shfl(srcAll, e, 64);
                bool ok = rmok && (e < cnt);
                unsigned sv = 0;
                if (ok) sv = stbf[(size_t)eid*RM + c];
                swp[j] = sv;
                xvp[j] = xbf[(s << 5) | c];         // src 0 for tail: killed by zero A
            }
        };
        auto tcompute = [&](const unsigned* swp, const uint2* xvp) {
            P Are, Aim, AimN;
            #pragma unroll
            for (int k2 = 0; k2 < 4; ++k2) {        // low halves = re, high = im
                unsigned a = swp[2*k2], b = swp[2*k2+1];
                Are.u[k2] = (a & 0xffffu) | (b << 16);
                Aim.u[k2] = (a >> 16)    | (b & 0xffff0000u);
                AimN.u[k2] = Aim.u[k2] ^ 0x80008000u;
            }
            P B;
            #pragma unroll
            for (int k2 = 0; k2 < 4; ++k2)          // Brh: re hi
                B.u[k2] = (xvp[2*k2].x & 0xffffu) | (xvp[2*k2+1].x << 16);
            Pre = __builtin_amdgcn_mfma_f32_32x32x16_bf16(Are.v, B.v, Pre, 0, 0, 0);
            Pim = __builtin_amdgcn_mfma_f32_32x32x16_bf16(Aim.v, B.v, Pim, 0, 0, 0);
            #pragma unroll
            for (int k2 = 0; k2 < 4; ++k2)          // Brl: re lo
                B.u[k2] = (xvp[2*k2].x >> 16) | (xvp[2*k2+1].x & 0xffff0000u);
            Pre = __builtin_amdgcn_mfma_f32_32x32x16_bf16(Are.v, B.v, Pre, 0, 0, 0);
            Pim = __builtin_amdgcn_mfma_f32_32x32x16_bf16(Aim.v, B.v, Pim, 0, 0, 0);
            #pragma unroll
            for (int k2 = 0; k2 < 4; ++k2)          // Bih: im hi
                B.u[k2] = (xvp[2*k2].y & 0xffffu) | (xvp[2*k2+1].y << 16);
            Pre = __builtin_amdgcn_mfma_f32_32x32x16_bf16(AimN.v, B.v, Pre, 0, 0, 0);
            Pim = __builtin_amdgcn_mfma_f32_32x32x16_bf16(Are.v, B.v, Pim, 0, 0, 0);
            #pragma unroll
            for (int k2 = 0; k2 < 4; ++k2)          // Bil: im lo
                B.u[k2] = (xvp[2*k2].y >> 16) | (xvp[2*k2+1].y & 0xffff0000u);
            Pre = __builtin_amdgcn_mfma_f32_32x32x16_bf16(AimN.v, B.v, Pre, 0, 0, 0);
            Pim = __builtin_amdgcn_mfma_f32_32x32x16_bf16(Are.v, B.v, Pim, 0, 0, 0);
        };

        if (ntiles > 0) {
            tload(0, sw, xv);
            for (int ck = 0; ck < ntiles; ++ck) {
                bool more = (ck + 1 < ntiles);
                if (more) tload(ck+1, swn, xvn);
                tcompute(sw, xv);
                if (more) {
                    #pragma unroll
                    for (int j = 0; j < 8; ++j) { sw[j] = swn[j]; xv[j] = xvn[j]; }
                }
            }
        }

        // C-extract: rows rm<18 -> aggS bf16 (deg==0 waves write zeros)
        short* aR = aggS + g*AROW;
        short* aI = aggS + NPB*AROW + g*AROW;
        #pragma unroll
        for (int reg = 0; reg < 16; ++reg) {
            int rm = (reg & 3) + 8*(reg >> 2) + 4*oct;
            if (rm < RM) {
                aR[rm*32 + c] = f2bf(Pre[reg]);
                aI[rm*32 + c] = f2bf(Pim[reg]);
            }
        }
        // residual K-block rows (FINAL: x, else zeros)
        if (l < 32) {
            float2 xvv = make_float2(0.f, 0.f);
            if (FINAL) xvv = xres[(size_t)n*CINC + l];
            aR[KK + l] = f2bf(xvv.x);
            aI[KK + l] = f2bf(xvv.y);
        }
    }
    __syncthreads();

    // ---- einsum via MFMA: D[m][d] = sum_k agg[m][k] * Wc[k][d], K=608 ----
    // 2-accumulator complex: Dre += ar*br + (-ai)*bi ; Dim += ar*bi + ai*br
    int quad = l >> 4;
    int nn16 = l & 15;
    int mrow = (nn16 < NPB) ? nn16 : NPB-1;       // rows >=4 ignored (dup of 3)
    int rm0 = (g < 3) ? 5*g : 15;                 // waves: 5,5,5,4 r-steps
    int nrm = (g < 3) ? 5 : 4;
    const short* aggR = aggS;
    const short* aggI = aggS + NPB*AROW;
    const short* Wr = Wcb;
    const short* Wi = Wcb + WSZ;
    int lbase = l*8;

    f32x4 Dre[2], Dim[2];
    #pragma unroll
    for (int nt = 0; nt < 2; ++nt) { Dre[nt] = (f32x4)(0.f); Dim[nt] = (f32x4)(0.f); }
    union PU { unsigned u[4]; bf16x8 v; };
    for (int r = rm0; r < rm0 + nrm; ++r) {
        int koff = r*32 + quad*8;
        bf16x8 ar = *(const bf16x8*)(aggR + mrow*AROW + koff);
        PU ai, ain;
        ai.v = *(const bf16x8*)(aggI + mrow*AROW + koff);
        #pragma unroll
        for (int k2 = 0; k2 < 4; ++k2) ain.u[k2] = ai.u[k2] ^ 0x80008000u;
        #pragma unroll
        for (int nt = 0; nt < 2; ++nt) {
            int woff = ((r*2 + nt) << 9) + lbase;     // fragment-major, coalesced
            bf16x8 br = *(const bf16x8*)(Wr + woff);
            bf16x8 bi = *(const bf16x8*)(Wi + woff);
            Dre[nt] = __builtin_amdgcn_mfma_f32_16x16x32_bf16(ar,    br, Dre[nt], 0, 0, 0);
            Dre[nt] = __builtin_amdgcn_mfma_f32_16x16x32_bf16(ain.v, bi, Dre[nt], 0, 0, 0);
            Dim[nt] = __builtin_amdgcn_mfma_f32_16x16x32_bf16(ar,    bi, Dim[nt], 0, 0, 0);
            Dim[nt] = __builtin_amdgcn_mfma_f32_16x16x32_bf16(ai.v,  br, Dim[nt], 0, 0, 0);
        }
    }
    __syncthreads();                    // all agg reads done; reuse as dump

    // ---- dump partials: [wave][m][d] float2, rows m<4 only (quad 0) ----
    float2* dump = (float2*)aggS;       // 4096 B <= 9984
    if (quad == 0) {
        #pragma unroll
        for (int reg = 0; reg < 4; ++reg) {
            int m = reg;
            #pragma unroll
            for (int nt = 0; nt < 2; ++nt) {
                int d = nt*16 + nn16;
                dump[((size_t)g*NPB + m)*COUTC + d] =
                    make_float2(Dre[nt][reg], Dim[nt][reg]);
            }
        }
    }
    __syncthreads();

    // ---- reduce 4 waves, nonlinearity (residual already in einsum) ----
    if (t < NPB*COUTC) {
        int m = t >> 5, d = t & 31;
        int nn = blockIdx.x*NPB + m;
        float2 hv = make_float2(0.f, 0.f);
        #pragma unroll
        for (int w = 0; w < NPB; ++w) {
            float2 v = dump[((size_t)w*NPB + m)*COUTC + d];
            hv.x += v.x; hv.y += v.y;
        }
        float mag = sqrtf(hv.x*hv.x + hv.y*hv.y);
        float num = mag + bias[d]; if (num < 0.f) num = 0.f;
        float den = (mag > EPSV) ? mag : EPSV;
        float f = num / den;
        if (FINAL) out[(size_t)nn*COUTC + d] = make_float2(f*hv.x, f*hv.y);
        else       outbf[(size_t)nn*COUTC + d] = packsplit(f*hv.x, f*hv.y);
    }
}

// ---------------- launch ----------------
extern "C" void kernel_launch(void* const* d_in, const int* in_sizes, int n_in,
                              void* d_out, int out_size, void* d_ws, size_t ws_size,
                              hipStream_t stream) {
    const float2* xc   = (const float2*)d_in[0];   // (N,32,2) -> complex
    const int*   edges = (const int*)  d_in[1];    // (E,2)
    const float2* stenc2 = (const float2*)d_in[2]; // (E,6,3,2) -> (E,18) complex
    const float* w1    = (const float*)d_in[3];
    const float* off1  = (const float*)d_in[4];
    const float* b1    = (const float*)d_in[5];
    const float* w2    = (const float*)d_in[6];
    const float* off2  = (const float*)d_in[7];
    const float* b2    = (const float*)d_in[8];
    const float2* resw = (const float2*)d_in[9];   // (32,32) complex
    float2* out = (float2*)d_out;

    char* ws = (char*)d_ws;
    size_t o = 0;
    auto alloc = [&](size_t bytes) {
        o = (o + 255) & ~(size_t)255;
        size_t r = o; o += bytes; return r;
    };
    int*      cursor = (int*)     (ws + alloc(NN*sizeof(int)));
    int2*     sei    = (int2*)    (ws + alloc((size_t)NN*CAP*sizeof(int2)));
    short*    Wcb1   = (short*)   (ws + alloc((size_t)2*WSZ*sizeof(short)));
    short*    Wcb2   = (short*)   (ws + alloc((size_t)2*WSZ*sizeof(short)));
    uint2*    xbf    = (uint2*)   (ws + alloc((size_t)NN*CINC*sizeof(uint2)));
    uint2*    hbf    = (uint2*)   (ws + alloc((size_t)NN*CINC*sizeof(uint2)));
    unsigned* stbf   = (unsigned*)(ws + alloc((size_t)EE*RM*sizeof(unsigned)));
    (void)ws_size; (void)in_sizes; (void)n_in; (void)out_size;

    hipMemsetAsync(cursor, 0, NN*sizeof(int), stream);
    k_build<<<(NN*CINC + 255)/256, 256, 0, stream>>>(edges, cursor, w1, off1, w2, off2,
                                                     Wcb1, Wcb2, sei, xc, xbf, resw,
                                                     stenc2, stbf);

    k_conv<false><<<NN/NPB, 256, 0, stream>>>(xbf, cursor, sei, stbf,
                                              Wcb1, b1, nullptr, nullptr, hbf);
    k_conv<true> <<<NN/NPB, 256, 0, stream>>>(hbf, cursor, sei, stbf,
                                              Wcb2, b2, xc, out, nullptr);
}

// Round 12
// 139.246 us; speedup vs baseline: 2.6650x; 1.0381x over previous
//
#include <hip/hip_runtime.h>
#include <hip/hip_bf16.h>

#define NN   10000
#define EE   160000
#define CINC 32
#define COUTC 32
#define RRR  6
#define MMM  3
#define RM   (RRR*MMM)      // 18
#define KK   (RM*CINC)      // 576
#define KE   608            // extended K: 576 + 32 residual block
#define NPB  4              // nodes per block (one wave each), 256 threads
#define CAP  64             // fixed bucket capacity per node (mean degree 16)
#define AROW 624            // agg row stride in bf16 elems (608 + 16 pad)
#define WSZ  19456          // shorts per Wt plane: 19*2*64*8
#define EPSV 1e-8f

typedef __attribute__((ext_vector_type(8))) short bf16x8;
typedef __attribute__((ext_vector_type(4))) float f32x4;
typedef __attribute__((ext_vector_type(16))) float f32x16;

__device__ inline short f2bf(float f) {            // native cast -> cvt_pk fusable
    __hip_bfloat16 b = __float2bfloat16(f);
    union { __hip_bfloat16 b; short s; } u; u.b = b;
    return u.s;
}
__device__ inline float bf2f(unsigned short h) {
    return __uint_as_float(((unsigned)h) << 16);
}
// split fp32 -> (hi, lo) bf16 pair, packed: x = rehi|relo<<16, y = imhi|imlo<<16
__device__ inline uint2 packsplit(float re, float im) {
    unsigned short rh = (unsigned short)f2bf(re);
    unsigned short rl = (unsigned short)f2bf(re - bf2f(rh));
    unsigned short ih = (unsigned short)f2bf(im);
    unsigned short il = (unsigned short)f2bf(im - bf2f(ih));
    return make_uint2((unsigned)rh | ((unsigned)rl << 16),
                      (unsigned)ih | ((unsigned)il << 16));
}

// ---------------- build: fragment-major bf16 weight planes + bucket scatter + x split ----------------
// Wt layout: addr(plane, r, n2, lane, kk) = plane*WSZ + ((r*2+n2)*64 + lane)*8 + kk.
// r=0..17: einsum K index k = r*32 + quad*8 + kk. r=18: residual block (Wcb2=resw,
// Wcb1=0), so the same einsum serves both convs.
__global__ void __launch_bounds__(256)
k_build(const int* __restrict__ edges, int* __restrict__ cursor,
        const float* __restrict__ w1, const float* __restrict__ off1,
        const float* __restrict__ w2, const float* __restrict__ off2,
        short* __restrict__ Wcb1, short* __restrict__ Wcb2,
        int2* __restrict__ sei,
        const float2* __restrict__ xc, uint2* __restrict__ xbf,
        const float2* __restrict__ resw)
{
    int i = blockIdx.x*blockDim.x + threadIdx.x;
    if (i < KK*COUTC) {
        int d = i & 31;
        int k = i >> 5;                 // einsum K index = rm*32 + c
        int c = k & 31;
        int r_ = k >> 5;                // 0..17
        int q  = (k >> 3) & 3;          // quad within r
        int kk = k & 7;
        int l  = q*16 + (d & 15);
        int n2 = d >> 4;
        int addr = ((r_*2 + n2)*64 + l)*8 + kk;
        float o1 = off1[c*COUTC + d];
        float o2 = off2[c*COUTC + d];
        float s1 = sinf(o1), c1 = cosf(o1);
        float s2 = sinf(o2), c2 = cosf(o2);
        Wcb1[addr]       = f2bf(w1[i]*c1);
        Wcb1[WSZ + addr] = f2bf(w1[i]*s1);
        Wcb2[addr]       = f2bf(w2[i]*c2);
        Wcb2[WSZ + addr] = f2bf(w2[i]*s2);
    }
    if (i < 1024) {                     // residual K-block (r=18): n2(2) x lane(64) x kk(8)
        int n2 = i >> 9;
        int l2 = (i >> 3) & 63;
        int kk = i & 7;
        int c  = ((l2 >> 4) << 3) + kk;
        int d  = (n2 << 4) + (l2 & 15);
        int addr = ((18*2 + n2)*64 + l2)*8 + kk;
        float2 rv = resw[c*COUTC + d];
        Wcb2[addr]       = f2bf(rv.x);
        Wcb2[WSZ + addr] = f2bf(rv.y);
        Wcb1[addr]       = 0;
        Wcb1[WSZ + addr] = 0;
    }
    if (i < EE) {
        int src = edges[2*i];
        int tgt = edges[2*i+1];
        int pos = atomicAdd(&cursor[tgt], 1);
        if (pos < CAP) sei[tgt*CAP + pos] = make_int2(src, i);
    }
    if (i < NN*CINC) {
        float2 v = xc[i];
        xbf[i] = packsplit(v.x, v.y);
    }
}

// ---------------- fused conv: in-register MFMA aggregation + bf16 MFMA einsum ----------------
// r9-verified structure (best-known-good). NO degree sort: node id = blockIdx*NPB
// + wave -> sei load issues at cycle 0. Lanes 0..31 load sei unconditionally;
// lanes 32..63 predicated on cnt. 16-edge K-tiles with 2-tile register double-
// buffer. NEW (r12): xres load hoisted to kernel top (FINAL) so it overlaps the
// whole agg phase instead of sitting on the post-agg serial path.
template<bool FINAL>
__global__ void __launch_bounds__(256, 4)
k_conv(const uint2* __restrict__ xbf,      // (NN,32) packed split-bf16 input
       const int*  __restrict__ cnts,      // (NN) per-node edge count (unclamped)
       const int2* __restrict__ sei,       // (NN*CAP) (src,eid) buckets
       const float4* __restrict__ stenc4,  // (EE,9) float4 = (EE,18) complex
       const short* __restrict__ Wcb,      // fragment-major [re|im] planes (19 r-blocks)
       const float* __restrict__ bias,     // (32)
       const float2* __restrict__ xres,    // (NN,32) original xc (FINAL only)
       float2* __restrict__ out,           // (NN,32) complex (FINAL)
       uint2* __restrict__ outbf)          // packed split-bf16 h (!FINAL)
{
    __shared__ __align__(16) short aggS[2*NPB*AROW];     // 9984 B; later dump
    int t = threadIdx.x;
    int g = t >> 6;                     // wave = node slot 0..3
    int l = t & 63;
    int c = l & 31;                     // channel (B col) == rm row index for A
    int oct = l >> 5;
    int n = blockIdx.x*NPB + g;         // node id: computable, no load

    // residual-row prefetch (independent of everything; overlaps agg)
    float2 xresv = make_float2(0.f, 0.f);
    if (FINAL && l < 32) xresv = xres[(size_t)n*CINC + l];

    // ---- aggregation via MFMA ----
    f32x16 Pre = (f32x16)(0.f), Pim = (f32x16)(0.f);
    {
        // sei load: lanes<32 immediate (no dependency), lanes>=32 wait on cnt
        int2 v0 = make_int2(0, 0);
        if (l < 32) v0 = sei[n*CAP + l];
        int cnt = cnts[n]; if (cnt > CAP) cnt = CAP;
        if (l >= 32 && l < cnt) v0 = sei[n*CAP + l];
        int srcAll = (l < cnt) ? v0.x : 0;
        int eidAll = (l < cnt) ? v0.y : 0;

        bool rmok = (c < RM);                       // A row valid
        int rmo = ((c >> 1) << 4) + ((c & 1) << 3); // byte offset of (re,im) in record
        const char* sb = (const char*)stenc4;
        int ntiles = (cnt + 15) >> 4;

        union P { unsigned u[4]; short s[8]; bf16x8 v; };
        float2 sv[8], svn[8];
        uint2  xv[8], xvn[8];

        auto tload = [&](int ck, float2* svp, uint2* xvp) {
            int ebase = ck*16 + oct*8;
            #pragma unroll
            for (int j = 0; j < 8; ++j) {
                int e = ebase + j;
                int eid = __shfl(eidAll, e, 64);
                int s   = __shfl(srcAll, e, 64);
                bool ok = rmok && (e < cnt);
                float2 vv = make_float2(0.f, 0.f);
                if (ok) vv = *(const float2*)(sb + (size_t)eid*144 + rmo);
                svp[j] = vv;
                xvp[j] = xbf[(s << 5) | c];         // src 0 for tail: killed by zero A
            }
        };
        auto tcompute = [&](const float2* svp, const uint2* xvp) {
            P Are, Aim, AimN;
            #pragma unroll
            for (int j = 0; j < 8; ++j) {
                Are.s[j] = f2bf(svp[j].x);
                Aim.s[j] = f2bf(svp[j].y);
            }
            #pragma unroll
            for (int k2 = 0; k2 < 4; ++k2) AimN.u[k2] = Aim.u[k2] ^ 0x80008000u;
            P B;
            #pragma unroll
            for (int k2 = 0; k2 < 4; ++k2)          // Brh: re hi
                B.u[k2] = (xvp[2*k2].x & 0xffffu) | (xvp[2*k2+1].x << 16);
            Pre = __builtin_amdgcn_mfma_f32_32x32x16_bf16(Are.v, B.v, Pre, 0, 0, 0);
            Pim = __builtin_amdgcn_mfma_f32_32x32x16_bf16(Aim.v, B.v, Pim, 0, 0, 0);
            #pragma unroll
            for (int k2 = 0; k2 < 4; ++k2)          // Brl: re lo
                B.u[k2] = (xvp[2*k2].x >> 16) | (xvp[2*k2+1].x & 0xffff0000u);
            Pre = __builtin_amdgcn_mfma_f32_32x32x16_bf16(Are.v, B.v, Pre, 0, 0, 0);
            Pim = __builtin_amdgcn_mfma_f32_32x32x16_bf16(Aim.v, B.v, Pim, 0, 0, 0);
            #pragma unroll
            for (int k2 = 0; k2 < 4; ++k2)          // Bih: im hi
                B.u[k2] = (xvp[2*k2].y & 0xffffu) | (xvp[2*k2+1].y << 16);
            Pre = __builtin_amdgcn_mfma_f32_32x32x16_bf16(AimN.v, B.v, Pre, 0, 0, 0);
            Pim = __builtin_amdgcn_mfma_f32_32x32x16_bf16(Are.v, B.v, Pim, 0, 0, 0);
            #pragma unroll
            for (int k2 = 0; k2 < 4; ++k2)          // Bil: im lo
                B.u[k2] = (xvp[2*k2].y >> 16) | (xvp[2*k2+1].y & 0xffff0000u);
            Pre = __builtin_amdgcn_mfma_f32_32x32x16_bf16(AimN.v, B.v, Pre, 0, 0, 0);
            Pim = __builtin_amdgcn_mfma_f32_32x32x16_bf16(Are.v, B.v, Pim, 0, 0, 0);
        };

        if (ntiles > 0) {
            tload(0, sv, xv);
            for (int ck = 0; ck < ntiles; ++ck) {
                bool more = (ck + 1 < ntiles);
                if (more) tload(ck+1, svn, xvn);
                tcompute(sv, xv);
                if (more) {
                    #pragma unroll
                    for (int j = 0; j < 8; ++j) { sv[j] = svn[j]; xv[j] = xvn[j]; }
                }
            }
        }

        // C-extract: rows rm<18 -> aggS bf16 (deg==0 waves write zeros)
        short* aR = aggS + g*AROW;
        short* aI = aggS + NPB*AROW + g*AROW;
        #pragma unroll
        for (int reg = 0; reg < 16; ++reg) {
            int rm = (reg & 3) + 8*(reg >> 2) + 4*oct;
            if (rm < RM) {
                aR[rm*32 + c] = f2bf(Pre[reg]);
                aI[rm*32 + c] = f2bf(Pim[reg]);
            }
        }
        // residual K-block rows (FINAL: prefetched x, else zeros)
        if (l < 32) {
            aR[KK + l] = f2bf(xresv.x);
            aI[KK + l] = f2bf(xresv.y);
        }
    }
    __syncthreads();

    // ---- einsum via MFMA: D[m][d] = sum_k agg[m][k] * Wc[k][d], K=608 ----
    // 2-accumulator complex: Dre += ar*br + (-ai)*bi ; Dim += ar*bi + ai*br
    int quad = l >> 4;
    int nn16 = l & 15;
    int mrow = (nn16 < NPB) ? nn16 : NPB-1;       // rows >=4 ignored (dup of 3)
    int rm0 = (g < 3) ? 5*g : 15;                 // waves: 5,5,5,4 r-steps
    int nrm = (g < 3) ? 5 : 4;
    const short* aggR = aggS;
    const short* aggI = aggS + NPB*AROW;
    const short* Wr = Wcb;
    const short* Wi = Wcb + WSZ;
    int lbase = l*8;

    f32x4 Dre[2], Dim[2];
    #pragma unroll
    for (int nt = 0; nt < 2; ++nt) { Dre[nt] = (f32x4)(0.f); Dim[nt] = (f32x4)(0.f); }
    union PU { unsigned u[4]; bf16x8 v; };
    for (int r = rm0; r < rm0 + nrm; ++r) {
        int koff = r*32 + quad*8;
        bf16x8 ar = *(const bf16x8*)(aggR + mrow*AROW + koff);
        PU ai, ain;
        ai.v = *(const bf16x8*)(aggI + mrow*AROW + koff);
        #pragma unroll
        for (int k2 = 0; k2 < 4; ++k2) ain.u[k2] = ai.u[k2] ^ 0x80008000u;
        #pragma unroll
        for (int nt = 0; nt < 2; ++nt) {
            int woff = ((r*2 + nt) << 9) + lbase;     // fragment-major, coalesced
            bf16x8 br = *(const bf16x8*)(Wr + woff);
            bf16x8 bi = *(const bf16x8*)(Wi + woff);
            Dre[nt] = __builtin_amdgcn_mfma_f32_16x16x32_bf16(ar,    br, Dre[nt], 0, 0, 0);
            Dre[nt] = __builtin_amdgcn_mfma_f32_16x16x32_bf16(ain.v, bi, Dre[nt], 0, 0, 0);
            Dim[nt] = __builtin_amdgcn_mfma_f32_16x16x32_bf16(ar,    bi, Dim[nt], 0, 0, 0);
            Dim[nt] = __builtin_amdgcn_mfma_f32_16x16x32_bf16(ai.v,  br, Dim[nt], 0, 0, 0);
        }
    }
    __syncthreads();                    // all agg reads done; reuse as dump

    // ---- dump partials: [wave][m][d] float2, rows m<4 only (quad 0) ----
    float2* dump = (float2*)aggS;       // 4096 B <= 9984
    if (quad == 0) {
        #pragma unroll
        for (int reg = 0; reg < 4; ++reg) {
            int m = reg;
            #pragma unroll
            for (int nt = 0; nt < 2; ++nt) {
                int d = nt*16 + nn16;
                dump[((size_t)g*NPB + m)*COUTC + d] =
                    make_float2(Dre[nt][reg], Dim[nt][reg]);
            }
        }
    }
    __syncthreads();

    // ---- reduce 4 waves, nonlinearity (residual already in einsum) ----
    if (t < NPB*COUTC) {
        int m = t >> 5, d = t & 31;
        int nn = blockIdx.x*NPB + m;
        float2 hv = make_float2(0.f, 0.f);
        #pragma unroll
        for (int w = 0; w < NPB; ++w) {
            float2 v = dump[((size_t)w*NPB + m)*COUTC + d];
            hv.x += v.x; hv.y += v.y;
        }
        float mag = sqrtf(hv.x*hv.x + hv.y*hv.y);
        float num = mag + bias[d]; if (num < 0.f) num = 0.f;
        float den = (mag > EPSV) ? mag : EPSV;
        float f = num / den;
        if (FINAL) out[(size_t)nn*COUTC + d] = make_float2(f*hv.x, f*hv.y);
        else       outbf[(size_t)nn*COUTC + d] = packsplit(f*hv.x, f*hv.y);
    }
}

// ---------------- launch ----------------
extern "C" void kernel_launch(void* const* d_in, const int* in_sizes, int n_in,
                              void* d_out, int out_size, void* d_ws, size_t ws_size,
                              hipStream_t stream) {
    const float2* xc   = (const float2*)d_in[0];   // (N,32,2) -> complex
    const int*   edges = (const int*)  d_in[1];    // (E,2)
    const float4* stenc4 = (const float4*)d_in[2]; // (E,6,3,2) -> (E,9) float4
    const float* w1    = (const float*)d_in[3];
    const float* off1  = (const float*)d_in[4];
    const float* b1    = (const float*)d_in[5];
    const float* w2    = (const float*)d_in[6];
    const float* off2  = (const float*)d_in[7];
    const float* b2    = (const float*)d_in[8];
    const float2* resw = (const float2*)d_in[9];   // (32,32) complex
    float2* out = (float2*)d_out;

    char* ws = (char*)d_ws;
    size_t o = 0;
    auto alloc = [&](size_t bytes) {
        o = (o + 255) & ~(size_t)255;
        size_t r = o; o += bytes; return r;
    };
    int*    cursor = (int*)  (ws + alloc(NN*sizeof(int)));
    int2*   sei    = (int2*) (ws + alloc((size_t)NN*CAP*sizeof(int2)));
    short*  Wcb1   = (short*)(ws + alloc((size_t)2*WSZ*sizeof(short)));
    short*  Wcb2   = (short*)(ws + alloc((size_t)2*WSZ*sizeof(short)));
    uint2*  xbf    = (uint2*)(ws + alloc((size_t)NN*CINC*sizeof(uint2)));
    uint2*  hbf    = (uint2*)(ws + alloc((size_t)NN*CINC*sizeof(uint2)));
    (void)ws_size; (void)in_sizes; (void)n_in; (void)out_size;

    hipMemsetAsync(cursor, 0, NN*sizeof(int), stream);
    k_build<<<(NN*CINC + 255)/256, 256, 0, stream>>>(edges, cursor, w1, off1, w2, off2,
                                                     Wcb1, Wcb2, sei, xc, xbf, resw);

    k_conv<false><<<NN/NPB, 256, 0, stream>>>(xbf, cursor, sei, stenc4,
                                              Wcb1, b1, nullptr, nullptr, hbf);
    k_conv<true> <<<NN/NPB, 256, 0, stream>>>(hbf, cursor, sei, stenc4,
                                              Wcb2, b2, xc, out, nullptr);
}